// Round 6
// baseline (564.709 us; speedup 1.0000x reference)
//
#include <hip/hip_runtime.h>
#include <math.h>

#define BB 8192
#define CC 5000
#define KTOP 20
#define MAXP 4096
#define MARGIN 0.5
#define ALPHA 0.5

// ws layout (bytes):
// 0      acc[3] doubles : bce_sum, dp, dn
// 24     int nmin
// 28     pad
// 32     counts[5000]
// 20032  flags[5000]
#define WS_ACC(ws)    ((double*)(ws))
#define WS_NMIN(ws)   ((int*)((char*)(ws) + 24))
#define WS_COUNTS(ws) ((int*)((char*)(ws) + 32))
#define WS_FLAGS(ws)  ((int*)((char*)(ws) + 20032))

__global__ void init_kernel(double* acc, int* nmin, int* counts) {
    int gid = blockIdx.x * blockDim.x + threadIdx.x;
    if (gid == 0) { acc[0] = 0.0; acc[1] = 0.0; acc[2] = 0.0; *nmin = 0; }
    for (int i = gid; i < CC; i += gridDim.x * blockDim.x) counts[i] = 0;
}

// fast BCE term via HW transcendentals (rel err ~1e-6, threshold 8e-3 abs)
__device__ __forceinline__ float bce_term_fast(float l, float t) {
    float e = __expf(-fabsf(l));
    float sp = __logf(1.0f + e);
    return fmaxf(l, 0.0f) - l * t + sp;
}

// Fused: BCE partial sum + per-class positive counts.
// grid (5, 256): c4 = col/4, 32 rows per thread, unrolled 8 groups x 4 rows
// so ~8 float4 loads stay in flight (VGPR cap 128 via launch_bounds(256,4)).
__global__ __launch_bounds__(256, 4)
void bce_counts_kernel(const float* __restrict__ logits, const float* __restrict__ target,
                       double* __restrict__ acc, int* __restrict__ counts) {
    int tid = threadIdx.x;
    int c4 = blockIdx.x * 256 + tid;            // float4 column index (0..1249)
    int r0 = blockIdx.y * 32;
    float bce = 0.0f;
    int cnt0 = 0, cnt1 = 0, cnt2 = 0, cnt3 = 0;
    if (c4 < 1250) {
        const float4* Lb = (const float4*)logits + (size_t)r0 * 1250 + c4;
        const float4* Tb = (const float4*)target + (size_t)r0 * 1250 + c4;
        #pragma unroll
        for (int rb = 0; rb < 32; rb += 4) {
            float4 lv[4], tv[4];
            #pragma unroll
            for (int u = 0; u < 4; ++u) {
                lv[u] = Lb[(size_t)(rb + u) * 1250];
                tv[u] = Tb[(size_t)(rb + u) * 1250];
            }
            #pragma unroll
            for (int u = 0; u < 4; ++u) {
                bce += bce_term_fast(lv[u].x, tv[u].x) + bce_term_fast(lv[u].y, tv[u].y)
                     + bce_term_fast(lv[u].z, tv[u].z) + bce_term_fast(lv[u].w, tv[u].w);
                cnt0 += (tv[u].x == 1.0f); cnt1 += (tv[u].y == 1.0f);
                cnt2 += (tv[u].z == 1.0f); cnt3 += (tv[u].w == 1.0f);
            }
        }
        int c = c4 * 4;
        if (cnt0) atomicAdd(&counts[c + 0], cnt0);
        if (cnt1) atomicAdd(&counts[c + 1], cnt1);
        if (cnt2) atomicAdd(&counts[c + 2], cnt2);
        if (cnt3) atomicAdd(&counts[c + 3], cnt3);
    }
    __shared__ double sd[256];
    sd[tid] = (double)bce;
    __syncthreads();
    for (int s = 128; s > 0; s >>= 1) {
        if (tid < s) sd[tid] += sd[tid + s];
        __syncthreads();
    }
    if (tid == 0) atomicAdd(&acc[0], sd[0]);
}

// class j kept iff count_j>1 AND sum_k count_k*[(count_k,k) <=lex (count_j,j)] <= BB/2
// One wave per class; also counts kept classes into nmin.
__global__ __launch_bounds__(256)
void minority_flag_kernel(const int* __restrict__ counts, int* __restrict__ flags,
                          int* __restrict__ nmin) {
    __shared__ int sc[CC];
    int tid = threadIdx.x;
    for (int i = tid; i < CC; i += 256) sc[i] = counts[i];
    __syncthreads();
    int wave = tid >> 6;
    int lane = tid & 63;
    int j = blockIdx.x * 4 + wave;
    if (j >= CC) return;
    int cj = sc[j];
    int flag = 0;
    if (cj > 1) {
        int cum = 0;
        for (int k = lane; k < CC; k += 64) {
            int ck = sc[k];
            if (ck < cj || (ck == cj && k <= j)) cum += ck;
        }
        for (int off = 32; off > 0; off >>= 1) cum += __shfl_down(cum, off);
        flag = (cum <= (BB / 2));
    }
    if (lane == 0) {
        flags[j] = flag;
        if (flag) atomicAdd(nmin, 1);
    }
}

// One block per CANDIDATE class (grid = 5000); non-minority blocks exit.
// launch_bounds(256,1): let the 64 staged column loads live in VGPRs.
__global__ __launch_bounds__(256, 1)
void crl_kernel(const float* __restrict__ logits, const float* __restrict__ target,
                const int* __restrict__ flags, double* __restrict__ acc) {
    int j = blockIdx.x;
    if (!flags[j]) return;

    __shared__ float pos[MAXP];
    __shared__ float neg_lds[KTOP * 256];   // transposed: [k][tid] -> conflict-free
    __shared__ float negsel[KTOP];
    __shared__ double sd[256];
    __shared__ int pcount;
    int tid = threadIdx.x;
    int lane = tid & 63;
    int wv = tid >> 6;

    if (tid == 0) pcount = 0;
    __syncthreads();

    // stage the whole column: 32 rows/thread, 64 scalar loads all in flight
    float xv[32], tv[32];
    #pragma unroll
    for (int i = 0; i < 32; ++i) {
        size_t r = (size_t)i * 256 + tid;
        tv[i] = target[r * CC + j];
        xv[i] = logits[r * CC + j];
    }

    // per-thread: sigmoid, positives -> LDS scatter, negatives -> branchless
    // register insertion top-20 (compile-time indices only; no LDS, no divergence)
    float lst[KTOP];
    #pragma unroll
    for (int k = 0; k < KTOP; ++k) lst[k] = INFINITY;
    #pragma unroll
    for (int i = 0; i < 32; ++i) {
        float x = xv[i];
        float e = __expf(-fabsf(x));
        float inv = __builtin_amdgcn_rcpf(1.0f + e);
        float s = (x >= 0.0f) ? inv : e * inv;
        bool isp = (tv[i] == 1.0f);
        if (isp) {
            int slot = atomicAdd(&pcount, 1);
            if (slot < MAXP) pos[slot] = s;
        }
        float v = isp ? INFINITY : s;
        #pragma unroll
        for (int k = KTOP - 1; k >= 1; --k) {
            // old lst[k-1], old lst[k] (written high->low, each slot written once)
            lst[k] = (v < lst[k - 1]) ? lst[k - 1] : ((v < lst[k]) ? v : lst[k]);
        }
        lst[0] = fminf(lst[0], v);
    }

    // dump sorted per-thread lists, transposed (addr = k*1024B + tid*4 -> 2 lanes/bank, free)
    #pragma unroll
    for (int k = 0; k < KTOP; ++k) neg_lds[k * 256 + tid] = lst[k];
    __syncthreads();

    // wave 0 merges the 256 sorted lists -> global top-20 (heads in registers)
    if (wv == 0) {
        int h0 = 0, h1 = 0, h2 = 0, h3 = 0;
        for (int round = 0; round < KTOP; ++round) {
            float v0 = (h0 < KTOP) ? neg_lds[h0 * 256 + lane      ] : INFINITY;
            float v1 = (h1 < KTOP) ? neg_lds[h1 * 256 + lane +  64] : INFINITY;
            float v2 = (h2 < KTOP) ? neg_lds[h2 * 256 + lane + 128] : INFINITY;
            float v3 = (h3 < KTOP) ? neg_lds[h3 * 256 + lane + 192] : INFINITY;
            float vm = fminf(fminf(v0, v1), fminf(v2, v3));
            float v = vm; int idx = lane;
            for (int o = 32; o > 0; o >>= 1) {
                float ov = __shfl_xor(v, o);
                int oi = __shfl_xor(idx, o);
                if (ov < v || (ov == v && oi < idx)) { v = ov; idx = oi; }
            }
            if (lane == 0) negsel[round] = v;
            if (lane == idx) {
                if (vm == v0) h0++;
                else if (vm == v1) h1++;
                else if (vm == v2) h2++;
                else h3++;
            }
        }
    }
    __syncthreads();

    int cp = min(pcount, MAXP);   // kept classes: 2 <= cp <= 4096

    // pad positives to pow2 and bitonic sort ascending (cp ~ 25 typically)
    int n = 1;
    while (n < cp) n <<= 1;
    for (int i = cp + tid; i < n; i += 256) pos[i] = INFINITY;
    __syncthreads();
    for (int k = 2; k <= n; k <<= 1) {
        for (int jj = k >> 1; jj > 0; jj >>= 1) {
            for (int i = tid; i < n; i += 256) {
                int ixj = i ^ jj;
                if (ixj > i) {
                    float a = pos[i], b = pos[ixj];
                    bool up = ((i & k) == 0);
                    if (up ? (a > b) : (a < b)) { pos[i] = b; pos[ixj] = a; }
                }
            }
            __syncthreads();
        }
    }

    int np_a = min(KTOP, cp - 1);
    int n_n = min(KTOP, BB - cp);   // 20 here

    // pos_sum: anchor at sorted rank r vs window [0..np_a] (self term = 0)
    double lsum = 0.0;
    for (int r = tid; r < cp; r += 256) {
        float v = pos[r];
        int L = (r <= np_a) ? np_a : np_a - 1;
        double s = 0.0;
        for (int l = 0; l <= L; ++l) s += (double)fabsf(v - pos[l]);
        lsum += s;
    }
    sd[tid] = lsum;
    __syncthreads();
    for (int s = 128; s > 0; s >>= 1) {
        if (tid < s) sd[tid] += sd[tid + s];
        __syncthreads();
    }
    double pos_sum = sd[0];
    __syncthreads();

    // neg_sum: all anchors vs 20 smallest negatives
    lsum = 0.0;
    for (int r = tid; r < cp; r += 256) {
        float v = pos[r];
        double s = 0.0;
        for (int l = 0; l < n_n; ++l) s += (double)fabsf(v - negsel[l]);
        lsum += s;
    }
    sd[tid] = lsum;
    __syncthreads();
    for (int s = 128; s > 0; s >>= 1) {
        if (tid < s) sd[tid] += sd[tid + s];
        __syncthreads();
    }
    if (tid == 0) {
        atomicAdd(&acc[1], (double)n_n * pos_sum);
        atomicAdd(&acc[2], (double)np_a * sd[0]);
    }
}

__global__ void finalize_kernel(const double* __restrict__ acc, const int* __restrict__ nmin,
                                float* __restrict__ out) {
    if (blockIdx.x == 0 && threadIdx.x == 0) {
        double bce = acc[0] / ((double)BB * (double)CC);
        double result;
        if (*nmin > 0) {
            double crl = acc[1] - acc[2] + MARGIN;
            if (crl < 0.0) crl = 0.0;
            result = ALPHA * crl + (1.0 - ALPHA) * bce;
        } else {
            result = bce;
        }
        out[0] = (float)result;
    }
}

extern "C" void kernel_launch(void* const* d_in, const int* in_sizes, int n_in,
                              void* d_out, int out_size, void* d_ws, size_t ws_size,
                              hipStream_t stream) {
    const float* logits = (const float*)d_in[0];
    const float* target = (const float*)d_in[1];
    float* out = (float*)d_out;

    double* acc  = WS_ACC(d_ws);
    int* nmin    = WS_NMIN(d_ws);
    int* counts  = WS_COUNTS(d_ws);
    int* flags   = WS_FLAGS(d_ws);

    init_kernel<<<20, 256, 0, stream>>>(acc, nmin, counts);
    bce_counts_kernel<<<dim3(5, 256), 256, 0, stream>>>(logits, target, acc, counts);
    minority_flag_kernel<<<1250, 256, 0, stream>>>(counts, flags, nmin);
    crl_kernel<<<CC, 256, 0, stream>>>(logits, target, flags, acc);
    finalize_kernel<<<1, 64, 0, stream>>>(acc, nmin, out);
}